// Round 16
// baseline (342.611 us; speedup 1.0000x reference)
//
#include <hip/hip_runtime.h>
#include <hip/hip_cooperative_groups.h>

namespace cg = cooperative_groups;

#define TID ((int)threadIdx.x)
typedef unsigned short u16;
typedef short short8 __attribute__((ext_vector_type(8)));
typedef float f32x4 __attribute__((ext_vector_type(4)));
typedef float v2f __attribute__((ext_vector_type(2)));

__device__ __forceinline__ u16 f2b(float f) {
    unsigned int x = __float_as_uint(f);
    return (u16)((x + 0x7fffu + ((x >> 16) & 1u)) >> 16);
}
__device__ __forceinline__ float b2f(u16 u) {
    return __uint_as_float(((unsigned int)u) << 16);
}
__device__ __forceinline__ v2f fma2(float a, v2f b, v2f c) {
    v2f av = {a, a};
    return __builtin_elementwise_fma(av, b, c);
}

// ---------------- workspace layout (BYTE offsets) ----------------
static constexpr size_t OFF_QW1   = 0;         // 800 f32 [32][25]
static constexpr size_t OFF_QWF2  = 3200;      // 5120 f32 [10][512]
static constexpr size_t OFF_TMAX  = 23680;     // 4 uint
static constexpr size_t OFF_SUM1C = 23808;     // f32 [8 copies][32]
static constexpr size_t OFF_SSQ1C = 24832;     // f32 [8][32]
static constexpr size_t OFF_SUM2  = 25856, OFF_SSQ2 = 26112;   // f32 [64]
static constexpr size_t OFF_SUM3  = 26368, OFF_SSQ3 = 28416;   // f32 [512]
static constexpr size_t STATS_BEG = 23680, STATS_END = 30464;
static constexpr size_t OFF_QW2C  = 30720;     // bf16 [25 shift][64 oc][32 ic]
static constexpr size_t OFF_QWF1C = 133120;    // bf16 [512][1024]
static constexpr size_t OFF_Y1P   = 1181696;   // bf16 [4096][144][32]  PRE-BN pooled conv1
static constexpr size_t OFF_H2P   = 38930432;  // bf16 [4096][1024]     PRE-BN pooled conv2
// total ~47.3 MB

// ---------------- abs-max of the 4 weight tensors ----------------
__global__ __launch_bounds__(256) void absmax_k(const float* w1, const float* w2,
                                                const float* wf1, const float* wf2,
                                                unsigned int* tmaxbits) {
    int bid = blockIdx.x;
    int b, lb, nb; const float* src; long n;
    if (bid < 1)        { b = 0; src = w1;  n = 800;    lb = bid;       nb = 1;   }
    else if (bid < 9)   { b = 1; src = w2;  n = 51200;  lb = bid - 1;   nb = 8;   }
    else if (bid < 265) { b = 2; src = wf1; n = 524288; lb = bid - 9;   nb = 256; }
    else                { b = 3; src = wf2; n = 5120;   lb = bid - 265; nb = 1;   }
    float m = 0.f;
    for (long i = (long)lb * 256 + TID; i < n; i += (long)nb * 256)
        m = fmaxf(m, fabsf(src[i]));
    __shared__ float red[256];
    red[TID] = m; __syncthreads();
    for (int s = 128; s > 0; s >>= 1) {
        if (TID < s) red[TID] = fmaxf(red[TID], red[TID + s]);
        __syncthreads();
    }
    if (TID == 0) atomicMax(&tmaxbits[b], __float_as_uint(red[0]));
}

// ---------------- all 4 quantizers in one launch ----------------
__global__ __launch_bounds__(256) void quant_all_k(const float* w1, const float* w2,
                                                   const float* wf1, const float* wf2,
                                                   float* qw1, u16* qw2c, u16* qwf1c,
                                                   float* qwf2, const unsigned int* tmax) {
    int bid = blockIdx.x;
    if (bid < 4) {
        int i = bid * 256 + TID; if (i >= 800) return;
        float t = 0.05f * __uint_as_float(tmax[0]);
        float v = w1[i];
        qw1[i] = (v > t) ? 1.f : ((v < -t) ? -1.f : 0.f);
    } else if (bid < 204) {
        int i = (bid - 4) * 256 + TID;       // < 51200
        float t = 0.05f * __uint_as_float(tmax[1]);
        int ic = i & 31, oc = (i >> 5) & 63, sh = i >> 11;
        float v = w2[(oc * 32 + ic) * 25 + sh];
        qw2c[i] = f2b((v > t) ? 1.f : ((v < -t) ? -1.f : 0.f));
    } else if (bid < 2252) {
        int i = (bid - 204) * 256 + TID;     // < 524288
        float t = 0.05f * __uint_as_float(tmax[2]);
        float v = wf1[i];
        qwf1c[i] = f2b((v > t) ? 1.f : ((v < -t) ? -1.f : 0.f));
    } else {
        int i = (bid - 2252) * 256 + TID;    // < 5120
        float t = 0.05f * __uint_as_float(tmax[3]);
        float v = wf2[i];
        qwf2[i] = (v > t) ? 1.f : ((v < -t) ? -1.f : 0.f);
    }
}

// ---------------- conv1 fused (scalar, known-good): conv ONCE + stats + pre-BN maxpool ----------------
__global__ __launch_bounds__(256) void conv1_fused_k(const float* __restrict__ x,
                                                     const float* __restrict__ qw1,
                                                     u16* __restrict__ y1p,
                                                     float* sum1c, float* ssq1c) {
    __shared__ float wl[800];
    __shared__ float red[4][64];
    for (int i = TID; i < 800; i += 256) wl[i] = qw1[i];
    __syncthreads();
    int p = blockIdx.x * 256 + TID;          // < 4096*384 (grid.x = 6144)
    int cg_ = p & 15, half = (p >> 4) & 1;
    int pr = p >> 5;                         // n*12 + py
    int py = pr % 12, n = pr / 12;
    int l = TID & 63, wv = TID >> 6;
    const float* xb = x + n * 784 + (2 * py) * 28 + half * 12;
    float patch[6][16];
    #pragma unroll
    for (int r = 0; r < 6; r++) {
        const float4* rp = reinterpret_cast<const float4*>(xb + r * 28);
        #pragma unroll
        for (int qq = 0; qq < 4; qq++) {
            float4 v = rp[qq];
            patch[r][qq * 4 + 0] = v.x; patch[r][qq * 4 + 1] = v.y;
            patch[r][qq * 4 + 2] = v.z; patch[r][qq * 4 + 3] = v.w;
        }
    }
    int c0 = cg_ * 2;
    v2f wp[25];
    #pragma unroll
    for (int k = 0; k < 25; k++)
        wp[k] = (v2f){wl[c0 * 25 + k], wl[(c0 + 1) * 25 + k]};
    v2f A0[12], A1[12];
    #pragma unroll
    for (int ox = 0; ox < 12; ox++) { A0[ox] = (v2f){0.f, 0.f}; A1[ox] = (v2f){0.f, 0.f}; }
    #pragma unroll
    for (int ky = 0; ky < 5; ky++)
        #pragma unroll
        for (int kx = 0; kx < 5; kx++) {
            v2f w = wp[ky * 5 + kx];
            #pragma unroll
            for (int ox = 0; ox < 12; ox++) {
                A0[ox] = fma2(patch[ky][ox + kx], w, A0[ox]);
                A1[ox] = fma2(patch[ky + 1][ox + kx], w, A1[ox]);
            }
        }
    v2f sv = {0.f, 0.f}, qv = {0.f, 0.f};
    #pragma unroll
    for (int ox = 0; ox < 12; ox++) {
        sv += A0[ox] + A1[ox];
        qv = __builtin_elementwise_fma(A0[ox], A0[ox], qv);
        qv = __builtin_elementwise_fma(A1[ox], A1[ox], qv);
    }
    float st[4] = {sv.x, sv.y, qv.x, qv.y};
    u16* base = y1p + (size_t)n * 4608 + (py * 12 + half * 6) * 32 + c0;
    #pragma unroll
    for (int j = 0; j < 6; j++) {
        v2f pm = __builtin_elementwise_max(
                     __builtin_elementwise_max(A0[2 * j], A0[2 * j + 1]),
                     __builtin_elementwise_max(A1[2 * j], A1[2 * j + 1]));
        unsigned int u = (unsigned int)f2b(pm.x) | ((unsigned int)f2b(pm.y) << 16);
        *reinterpret_cast<unsigned int*>(base + j * 32) = u;
    }
    #pragma unroll
    for (int t = 0; t < 4; t++) {
        st[t] += __shfl_xor(st[t], 16);
        st[t] += __shfl_xor(st[t], 32);
    }
    if (l < 16) {
        #pragma unroll
        for (int t = 0; t < 4; t++) red[wv][l * 4 + t] = st[t];
    }
    __syncthreads();
    if (TID < 64) {
        float v = red[0][TID] + red[1][TID] + red[2][TID] + red[3][TID];
        int t = TID & 3, ch = (TID >> 2) * 2 + (t & 1);
        float* dst = (t < 2 ? sum1c : ssq1c) + (blockIdx.x & 7) * 32 + ch;
        atomicAdd(dst, v);
    }
}

// ---------------- conv2: MFMA implicit conv; BN1+relu in staging; pre-BN pooled epilogue ----------------
__global__ __launch_bounds__(256) void conv2_k(const u16* __restrict__ y1p,
                                               const u16* __restrict__ qw2c,
                                               u16* __restrict__ h2pre,
                                               const float* sum1c, const float* ssq1c,
                                               const float* g1, const float* be1,
                                               float* sum, float* ssq) {
    __shared__ float4 hsm4[1176];            // 2 x 9408 B
    __shared__ float scs[32], shs[32];
    char* hsraw = (char*)hsm4;
    int n0 = blockIdx.x * 8;                 // grid.x = 512
    int l = TID & 63, wv = TID >> 6;
    int oc0 = wv * 16;
    int lm = l & 15, lr = (l >> 3) & 1, ox = l & 7, bq = l >> 4;
    if (TID < 32) {
        float s = 0.f, q = 0.f;
        #pragma unroll
        for (int r = 0; r < 8; r++) { s += sum1c[r * 32 + TID]; q += ssq1c[r * 32 + TID]; }
        float m = s * (1.f / 2359296.f);
        float v = q * (1.f / 2359296.f) - m * m;
        float sc = g1[TID] / sqrtf(v + 1e-5f);
        scs[TID] = sc; shs[TID] = be1[TID] - m * sc;
    }
    __syncthreads();
    float scR[8], shR[8];
    {
        int b = TID & 3;
        #pragma unroll
        for (int j = 0; j < 8; j++) { scR[j] = scs[b * 8 + j]; shR[j] = shs[b * 8 + j]; }
    }
    short8 bw[25];
    #pragma unroll
    for (int sh = 0; sh < 25; sh++)
        bw[sh] = *reinterpret_cast<const short8*>(qw2c + ((size_t)sh * 64 + oc0 + lm) * 32 + bq * 8);
    int xy[5];
    #pragma unroll
    for (int kx = 0; kx < 5; kx++) {
        int xx = ox + kx;
        xy[kx] = lr * 784 + xx * 64 + (((bq + (xx >> 1)) & 3) * 16);
    }
    float sacc = 0.f, s2acc = 0.f;
    {
        const uint4* src = reinterpret_cast<const uint4*>(y1p + (size_t)n0 * 4608);
        #pragma unroll
        for (int k = 0; k < 3; k++) {
            if (k < 2 || TID < 64) {
                int i = TID + k * 256;
                int pix = i >> 2, b = i & 3;
                int y = pix / 12, xx = pix - y * 12;
                union { uint4 v; u16 u[8]; } in, out;
                in.v = src[i];
                #pragma unroll
                for (int j = 0; j < 8; j++)
                    out.u[j] = f2b(fmaxf(fmaf(b2f(in.u[j]), scR[j], shR[j]), 0.f));
                *reinterpret_cast<uint4*>(hsraw + y * 784 + xx * 64 + (((b + (xx >> 1)) & 3) * 16)) = out.v;
            }
        }
    }
    #pragma unroll 1
    for (int s = 0; s < 8; s++) {
        __syncthreads();
        if (s < 7) {
            const uint4* src = reinterpret_cast<const uint4*>(y1p + (size_t)(n0 + s + 1) * 4608);
            char* dst = hsraw + ((s + 1) & 1) * 9408;
            #pragma unroll
            for (int k = 0; k < 3; k++) {
                if (k < 2 || TID < 64) {
                    int i = TID + k * 256;
                    int pix = i >> 2, b = i & 3;
                    int y = pix / 12, xx = pix - y * 12;
                    union { uint4 v; u16 u[8]; } in, out;
                    in.v = src[i];
                    #pragma unroll
                    for (int j = 0; j < 8; j++)
                        out.u[j] = f2b(fmaxf(fmaf(b2f(in.u[j]), scR[j], shR[j]), 0.f));
                    *reinterpret_cast<uint4*>(dst + y * 784 + xx * 64 + (((b + (xx >> 1)) & 3) * 16)) = out.v;
                }
            }
        }
        const char* hb = hsraw + (s & 1) * 9408;
        f32x4 acc[4] = {{0.f,0.f,0.f,0.f},{0.f,0.f,0.f,0.f},{0.f,0.f,0.f,0.f},{0.f,0.f,0.f,0.f}};
        #pragma unroll
        for (int R = 0; R <= 10; R++) {
            short8 a[5];
            #pragma unroll
            for (int kx = 0; kx < 5; kx++)
                a[kx] = *reinterpret_cast<const short8*>(hb + xy[kx] + R * 784);
            #pragma unroll
            for (int mt = 0; mt < 4; mt++) {
                int ky = R - 2 * mt;
                if (ky < 0 || ky > 4) continue;
                #pragma unroll
                for (int kx = 0; kx < 5; kx++)
                    acc[mt] = __builtin_amdgcn_mfma_f32_16x16x32_bf16(a[kx], bw[ky * 5 + kx], acc[mt], 0, 0, 0);
            }
        }
        int n = n0 + s;
        u16* hp = h2pre + (size_t)n * 1024 + (oc0 + lm) * 16;
        #pragma unroll
        for (int mt = 0; mt < 4; mt++) {
            float v0 = acc[mt][0], v1 = acc[mt][1], v2 = acc[mt][2], v3 = acc[mt][3];
            sacc += v0 + v1 + v2 + v3;
            s2acc += v0 * v0 + v1 * v1 + v2 * v2 + v3 * v3;
            float w0 = fmaxf(v0, v1), w1 = fmaxf(v2, v3);
            float p0 = fmaxf(w0, __shfl_xor(w0, 32));
            float p1 = fmaxf(w1, __shfl_xor(w1, 32));
            if (bq < 2) {
                unsigned int u = (unsigned int)f2b(p0) | ((unsigned int)f2b(p1) << 16);
                *reinterpret_cast<unsigned int*>(hp + mt * 4 + bq * 2) = u;
            }
        }
    }
    sacc  += __shfl_xor(sacc, 16);  sacc  += __shfl_xor(sacc, 32);
    s2acc += __shfl_xor(s2acc, 16); s2acc += __shfl_xor(s2acc, 32);
    if (l < 16) { atomicAdd(&sum[oc0 + l], sacc); atomicAdd(&ssq[oc0 + l], s2acc); }
}

// ---------------- fc12: cooperative fused fc1 + BN3 + relu + fc2 ----------------
// 256 blocks (1/CU guaranteed: 4 waves, ~37KB LDS) = 32 mb x 8 jb; each block runs
// 2 m-tiles of the 64x64 fc1 (BN2+relu fused in A-staging), atomic-adds BN3 stats,
// grid-syncs, then applies BN3+relu IN-REGISTER and reduces its 64-j slice against
// wf2 into out via atomics. y3 (16.8MB traffic) and fc2_k are deleted.
__global__ __launch_bounds__(256) void fc12_k(const u16* __restrict__ h2pre,
                                              const u16* __restrict__ qwf1c,
                                              const float* sum2, const float* ssq2,
                                              const float* g2, const float* be2,
                                              const float* __restrict__ qwf2,
                                              const float* g3, const float* be3,
                                              const float* bf2,
                                              float* sum3, float* ssq3,
                                              float* __restrict__ out) {
    __shared__ float4 Asm[576], Bsm[576];
    __shared__ float sc2s[64], sh2s[64];
    __shared__ u16 vls[64 * 74];             // 74-stride: bank = 37*m mod 32 (odd) -> <=2-way
    __shared__ float part[3][640];
    __shared__ float wsl[640];               // wf2 slice [64 j][10 o]
    u16* AsU = (u16*)Asm; u16* BsU = (u16*)Bsm;
    int bid = blockIdx.x;                    // grid = 256
    int jb = bid & 7, mb = bid >> 3;
    int j0 = jb * 64;
    int l = TID & 63, wv = TID >> 6;
    int lm = l & 15, q = l >> 4;
    int r0 = TID >> 3, c0 = TID & 7;
    if (TID < 64) {
        float m = sum2[TID] * (1.f / 262144.f);
        float v = ssq2[TID] * (1.f / 262144.f) - m * m;
        float s = g2[TID] / sqrtf(v + 1e-5f);
        sc2s[TID] = s; sh2s[TID] = be2[TID] - m * s;
    }
    for (int i = TID; i < 640; i += 256) {
        int jj = i / 10, o = i - jj * 10;
        wsl[jj * 10 + o] = qwf2[o * 512 + j0 + jj];
    }
    __syncthreads();
    f32x4 acc[2][4] = {};
    #pragma unroll 1
    for (int t = 0; t < 2; t++) {
        int m0 = (mb * 2 + t) * 64;
        #pragma unroll 1
        for (int kc = 0; kc < 16; kc++) {
            int kk = kc * 64;
            if (kc | t) __syncthreads();
            int oc = (kk + c0 * 8) >> 4;
            float sc = sc2s[oc], sh = sh2s[oc];
            #pragma unroll
            for (int i = 0; i < 2; i++) {
                int r = i * 32 + r0;
                union { float4 v; u16 h[8]; } in, o;
                in.v = *reinterpret_cast<const float4*>(h2pre + (size_t)(m0 + r) * 1024 + kk + c0 * 8);
                #pragma unroll
                for (int e = 0; e < 8; e++)
                    o.h[e] = f2b(fmaxf(fmaf(b2f(in.h[e]), sc, sh), 0.f));
                *reinterpret_cast<float4*>(AsU + r * 72 + c0 * 8) = o.v;
                *reinterpret_cast<float4*>(BsU + r * 72 + c0 * 8) =
                    *reinterpret_cast<const float4*>(qwf1c + (size_t)(j0 + r) * 1024 + kk + c0 * 8);
            }
            __syncthreads();
            #pragma unroll
            for (int half = 0; half < 2; half++) {
                short8 b = *reinterpret_cast<const short8*>(BsU + (wv * 16 + lm) * 72 + half * 32 + q * 8);
                #pragma unroll
                for (int mt = 0; mt < 4; mt++) {
                    short8 a = *reinterpret_cast<const short8*>(AsU + (mt * 16 + lm) * 72 + half * 32 + q * 8);
                    acc[t][mt] = __builtin_amdgcn_mfma_f32_16x16x32_bf16(a, b, acc[t][mt], 0, 0, 0);
                }
            }
        }
    }
    // BN3 stats over both tiles (j = j0 + wv*16 + lm for all 32 values of this lane)
    float s = 0.f, s2 = 0.f;
    #pragma unroll
    for (int t = 0; t < 2; t++)
        #pragma unroll
        for (int mt = 0; mt < 4; mt++)
            #pragma unroll
            for (int i = 0; i < 4; i++) { float v = acc[t][mt][i]; s += v; s2 = fmaf(v, v, s2); }
    s  += __shfl_xor(s, 16);  s  += __shfl_xor(s, 32);
    s2 += __shfl_xor(s2, 16); s2 += __shfl_xor(s2, 32);
    if (l < 16) {
        atomicAdd(&sum3[j0 + wv * 16 + l], s);
        atomicAdd(&ssq3[j0 + wv * 16 + l], s2);
    }
    __threadfence();
    cg::this_grid().sync();
    // phase 2: BN3 finalize for this lane's j, then j-slice GEMV into out
    int j = j0 + wv * 16 + lm;
    float m3 = sum3[j] * (1.f / 4096.f);
    float v3 = ssq3[j] * (1.f / 4096.f) - m3 * m3;
    float sc3 = g3[j] / sqrtf(v3 + 1e-5f);
    float sh3 = be3[j] - m3 * sc3;
    int jl = wv * 16 + lm;
    int ml = TID & 63, grp = TID >> 6;
    #pragma unroll 1
    for (int t = 0; t < 2; t++) {
        int m0 = (mb * 2 + t) * 64;
        __syncthreads();
        #pragma unroll
        for (int mt = 0; mt < 4; mt++)
            #pragma unroll
            for (int i = 0; i < 4; i++) {
                int mrow = mt * 16 + q * 4 + i;
                vls[mrow * 74 + jl] = f2b(fmaxf(fmaf(acc[t][mt][i], sc3, sh3), 0.f));
            }
        __syncthreads();
        float o10[10] = {};
        #pragma unroll
        for (int jj = 0; jj < 16; jj++) {
            float vj = b2f(vls[ml * 74 + grp * 16 + jj]);
            #pragma unroll
            for (int o = 0; o < 10; o++)
                o10[o] = fmaf(vj, wsl[(grp * 16 + jj) * 10 + o], o10[o]);
        }
        if (grp > 0) {
            #pragma unroll
            for (int o = 0; o < 10; o++) part[grp - 1][o * 64 + ml] = o10[o];
        }
        __syncthreads();
        if (grp == 0) {
            #pragma unroll
            for (int o = 0; o < 10; o++) {
                float r = o10[o] + part[0][o * 64 + ml] + part[1][o * 64 + ml]
                          + part[2][o * 64 + ml] + (jb == 0 ? bf2[o] : 0.f);
                atomicAdd(&out[(m0 + ml) * 10 + o], r);
            }
        }
    }
}

extern "C" void kernel_launch(void* const* d_in, const int* in_sizes, int n_in,
                              void* d_out, int out_size, void* d_ws, size_t ws_size,
                              hipStream_t stream) {
    char* wsb = (char*)d_ws;
    const float* x   = (const float*)d_in[0];
    const float* w1  = (const float*)d_in[1];
    // b1/b2/bf1 cancel under training-mode BN
    const float* g1  = (const float*)d_in[3];
    const float* be1 = (const float*)d_in[4];
    const float* w2  = (const float*)d_in[5];
    const float* g2  = (const float*)d_in[7];
    const float* be2 = (const float*)d_in[8];
    const float* wf1 = (const float*)d_in[9];
    const float* g3  = (const float*)d_in[11];
    const float* be3 = (const float*)d_in[12];
    const float* wf2 = (const float*)d_in[13];
    const float* bf2 = (const float*)d_in[14];
    float* out = (float*)d_out;

    unsigned int* tmax = (unsigned int*)(wsb + OFF_TMAX);
    float* qw1   = (float*)(wsb + OFF_QW1);
    float* qwf2  = (float*)(wsb + OFF_QWF2);
    u16*   qw2c  = (u16*)(wsb + OFF_QW2C);
    u16*   qwf1c = (u16*)(wsb + OFF_QWF1C);
    u16*   y1p   = (u16*)(wsb + OFF_Y1P);
    u16*   h2pre = (u16*)(wsb + OFF_H2P);

    float* sum1c = (float*)(wsb + OFF_SUM1C); float* ssq1c = (float*)(wsb + OFF_SSQ1C);
    float* sum2  = (float*)(wsb + OFF_SUM2);  float* ssq2  = (float*)(wsb + OFF_SSQ2);
    float* sum3  = (float*)(wsb + OFF_SUM3);  float* ssq3  = (float*)(wsb + OFF_SSQ3);

    hipMemsetAsync(wsb + STATS_BEG, 0, STATS_END - STATS_BEG, stream);
    hipMemsetAsync(out, 0, 4096 * 10 * sizeof(float), stream);   // fc12 accumulates via atomics

    absmax_k<<<266, 256, 0, stream>>>(w1, w2, wf1, wf2, tmax);
    quant_all_k<<<2272, 256, 0, stream>>>(w1, w2, wf1, wf2, qw1, qw2c, qwf1c, qwf2, tmax);

    conv1_fused_k<<<6144, 256, 0, stream>>>(x, qw1, y1p, sum1c, ssq1c);
    conv2_k<<<512, 256, 0, stream>>>(y1p, qw2c, h2pre, sum1c, ssq1c, g1, be1, sum2, ssq2);

    void* args[] = {(void*)&h2pre, (void*)&qwf1c, (void*)&sum2, (void*)&ssq2,
                    (void*)&g2, (void*)&be2, (void*)&qwf2, (void*)&g3, (void*)&be3,
                    (void*)&bf2, (void*)&sum3, (void*)&ssq3, (void*)&out};
    hipLaunchCooperativeKernel((void*)fc12_k, dim3(256), dim3(256), args, 0, stream);
}

// Round 17
// 226.183 us; speedup vs baseline: 1.5148x; 1.5148x over previous
//
#include <hip/hip_runtime.h>

#define TID ((int)threadIdx.x)
typedef unsigned short u16;
typedef short short8 __attribute__((ext_vector_type(8)));
typedef float f32x4 __attribute__((ext_vector_type(4)));
typedef float v2f __attribute__((ext_vector_type(2)));

__device__ __forceinline__ u16 f2b(float f) {
    unsigned int x = __float_as_uint(f);
    return (u16)((x + 0x7fffu + ((x >> 16) & 1u)) >> 16);
}
__device__ __forceinline__ float b2f(u16 u) {
    return __uint_as_float(((unsigned int)u) << 16);
}
__device__ __forceinline__ v2f fma2(float a, v2f b, v2f c) {
    v2f av = {a, a};
    return __builtin_elementwise_fma(av, b, c);
}

// ---------------- workspace layout (BYTE offsets) ----------------
static constexpr size_t OFF_QW1   = 0;         // 800 f32 [32][25]
static constexpr size_t OFF_QWF2  = 3200;      // 5120 f32 [10][512]
static constexpr size_t OFF_TMAX  = 23680;     // 4 uint
static constexpr size_t OFF_SUM1C = 23808;     // f32 [8 copies][32]
static constexpr size_t OFF_SSQ1C = 24832;     // f32 [8][32]
static constexpr size_t OFF_SUM2  = 25856, OFF_SSQ2 = 26112;   // f32 [64]
static constexpr size_t OFF_SUM3  = 26368, OFF_SSQ3 = 28416;   // f32 [512]
static constexpr size_t STATS_BEG = 23680, STATS_END = 30464;
static constexpr size_t OFF_QW2C  = 30720;     // bf16 [25 shift][64 oc][32 ic]
static constexpr size_t OFF_QWF1C = 133120;    // bf16 [512][1024]
static constexpr size_t OFF_Y1P   = 1181696;   // bf16 [4096][144][32]  PRE-BN pooled conv1
static constexpr size_t OFF_H2P   = 38930432;  // bf16 [4096][1024]     PRE-BN pooled conv2
static constexpr size_t OFF_Y3    = 47319040;  // f32 [512][4096]
// total ~55.7 MB

// ---------------- abs-max of the 4 weight tensors ----------------
__global__ __launch_bounds__(256) void absmax_k(const float* w1, const float* w2,
                                                const float* wf1, const float* wf2,
                                                unsigned int* tmaxbits) {
    int bid = blockIdx.x;
    int b, lb, nb; const float* src; long n;
    if (bid < 1)        { b = 0; src = w1;  n = 800;    lb = bid;       nb = 1;   }
    else if (bid < 9)   { b = 1; src = w2;  n = 51200;  lb = bid - 1;   nb = 8;   }
    else if (bid < 265) { b = 2; src = wf1; n = 524288; lb = bid - 9;   nb = 256; }
    else                { b = 3; src = wf2; n = 5120;   lb = bid - 265; nb = 1;   }
    float m = 0.f;
    for (long i = (long)lb * 256 + TID; i < n; i += (long)nb * 256)
        m = fmaxf(m, fabsf(src[i]));
    __shared__ float red[256];
    red[TID] = m; __syncthreads();
    for (int s = 128; s > 0; s >>= 1) {
        if (TID < s) red[TID] = fmaxf(red[TID], red[TID + s]);
        __syncthreads();
    }
    if (TID == 0) atomicMax(&tmaxbits[b], __float_as_uint(red[0]));
}

// ---------------- all 4 quantizers in one launch ----------------
__global__ __launch_bounds__(256) void quant_all_k(const float* w1, const float* w2,
                                                   const float* wf1, const float* wf2,
                                                   float* qw1, u16* qw2c, u16* qwf1c,
                                                   float* qwf2, const unsigned int* tmax) {
    int bid = blockIdx.x;
    if (bid < 4) {
        int i = bid * 256 + TID; if (i >= 800) return;
        float t = 0.05f * __uint_as_float(tmax[0]);
        float v = w1[i];
        qw1[i] = (v > t) ? 1.f : ((v < -t) ? -1.f : 0.f);
    } else if (bid < 204) {
        int i = (bid - 4) * 256 + TID;       // < 51200
        float t = 0.05f * __uint_as_float(tmax[1]);
        int ic = i & 31, oc = (i >> 5) & 63, sh = i >> 11;
        float v = w2[(oc * 32 + ic) * 25 + sh];
        qw2c[i] = f2b((v > t) ? 1.f : ((v < -t) ? -1.f : 0.f));
    } else if (bid < 2252) {
        int i = (bid - 204) * 256 + TID;     // < 524288
        float t = 0.05f * __uint_as_float(tmax[2]);
        float v = wf1[i];
        qwf1c[i] = f2b((v > t) ? 1.f : ((v < -t) ? -1.f : 0.f));
    } else {
        int i = (bid - 2252) * 256 + TID;    // < 5120
        float t = 0.05f * __uint_as_float(tmax[3]);
        float v = wf2[i];
        qwf2[i] = (v > t) ? 1.f : ((v < -t) ? -1.f : 0.f);
    }
}

// ---------------- conv1 fused (scalar): conv ONCE + stats + pre-BN maxpool ----------------
// Round-17: __launch_bounds__(256,2) — at the default the compiler picked 64 VGPR
// (8-wave target) and re-materialized the 96-reg patch instead of keeping it
// resident; ≤256 VGPR lets patch+weights+accs live in registers (ideal 24 loads).
__global__ __launch_bounds__(256, 2) void conv1_fused_k(const float* __restrict__ x,
                                                        const float* __restrict__ qw1,
                                                        u16* __restrict__ y1p,
                                                        float* sum1c, float* ssq1c) {
    __shared__ float wl[800];
    __shared__ float red[4][64];
    for (int i = TID; i < 800; i += 256) wl[i] = qw1[i];
    __syncthreads();
    int p = blockIdx.x * 256 + TID;          // < 4096*384 (grid.x = 6144)
    int cg_ = p & 15, half = (p >> 4) & 1;
    int pr = p >> 5;                         // n*12 + py
    int py = pr % 12, n = pr / 12;
    int l = TID & 63, wv = TID >> 6;
    const float* xb = x + n * 784 + (2 * py) * 28 + half * 12;
    float patch[6][16];
    #pragma unroll
    for (int r = 0; r < 6; r++) {
        const float4* rp = reinterpret_cast<const float4*>(xb + r * 28);
        #pragma unroll
        for (int qq = 0; qq < 4; qq++) {
            float4 v = rp[qq];
            patch[r][qq * 4 + 0] = v.x; patch[r][qq * 4 + 1] = v.y;
            patch[r][qq * 4 + 2] = v.z; patch[r][qq * 4 + 3] = v.w;
        }
    }
    int c0 = cg_ * 2;
    v2f wp[25];
    #pragma unroll
    for (int k = 0; k < 25; k++)
        wp[k] = (v2f){wl[c0 * 25 + k], wl[(c0 + 1) * 25 + k]};
    v2f A0[12], A1[12];
    #pragma unroll
    for (int ox = 0; ox < 12; ox++) { A0[ox] = (v2f){0.f, 0.f}; A1[ox] = (v2f){0.f, 0.f}; }
    #pragma unroll
    for (int ky = 0; ky < 5; ky++)
        #pragma unroll
        for (int kx = 0; kx < 5; kx++) {
            v2f w = wp[ky * 5 + kx];
            #pragma unroll
            for (int ox = 0; ox < 12; ox++) {
                A0[ox] = fma2(patch[ky][ox + kx], w, A0[ox]);
                A1[ox] = fma2(patch[ky + 1][ox + kx], w, A1[ox]);
            }
        }
    v2f sv = {0.f, 0.f}, qv = {0.f, 0.f};
    #pragma unroll
    for (int ox = 0; ox < 12; ox++) {
        sv += A0[ox] + A1[ox];
        qv = __builtin_elementwise_fma(A0[ox], A0[ox], qv);
        qv = __builtin_elementwise_fma(A1[ox], A1[ox], qv);
    }
    float st[4] = {sv.x, sv.y, qv.x, qv.y};
    u16* base = y1p + (size_t)n * 4608 + (py * 12 + half * 6) * 32 + c0;
    #pragma unroll
    for (int j = 0; j < 6; j++) {
        v2f pm = __builtin_elementwise_max(
                     __builtin_elementwise_max(A0[2 * j], A0[2 * j + 1]),
                     __builtin_elementwise_max(A1[2 * j], A1[2 * j + 1]));
        unsigned int u = (unsigned int)f2b(pm.x) | ((unsigned int)f2b(pm.y) << 16);
        *reinterpret_cast<unsigned int*>(base + j * 32) = u;
    }
    #pragma unroll
    for (int t = 0; t < 4; t++) {
        st[t] += __shfl_xor(st[t], 16);
        st[t] += __shfl_xor(st[t], 32);
    }
    if (l < 16) {
        #pragma unroll
        for (int t = 0; t < 4; t++) red[wv][l * 4 + t] = st[t];
    }
    __syncthreads();
    if (TID < 64) {
        float v = red[0][TID] + red[1][TID] + red[2][TID] + red[3][TID];
        int t = TID & 3, ch = (TID >> 2) * 2 + (t & 1);
        float* dst = (t < 2 ? sum1c : ssq1c) + (blockIdx.x & 7) * 32 + ch;
        atomicAdd(dst, v);
    }
}

// ---------------- conv2: MFMA implicit conv; BN1+relu in staging; pre-BN pooled epilogue ----------------
__global__ __launch_bounds__(256) void conv2_k(const u16* __restrict__ y1p,
                                               const u16* __restrict__ qw2c,
                                               u16* __restrict__ h2pre,
                                               const float* sum1c, const float* ssq1c,
                                               const float* g1, const float* be1,
                                               float* sum, float* ssq) {
    __shared__ float4 hsm4[1176];            // 2 x 9408 B
    __shared__ float scs[32], shs[32];
    char* hsraw = (char*)hsm4;
    int n0 = blockIdx.x * 8;                 // grid.x = 512
    int l = TID & 63, wv = TID >> 6;
    int oc0 = wv * 16;
    int lm = l & 15, lr = (l >> 3) & 1, ox = l & 7, bq = l >> 4;
    if (TID < 32) {
        float s = 0.f, q = 0.f;
        #pragma unroll
        for (int r = 0; r < 8; r++) { s += sum1c[r * 32 + TID]; q += ssq1c[r * 32 + TID]; }
        float m = s * (1.f / 2359296.f);
        float v = q * (1.f / 2359296.f) - m * m;
        float sc = g1[TID] / sqrtf(v + 1e-5f);
        scs[TID] = sc; shs[TID] = be1[TID] - m * sc;
    }
    __syncthreads();
    float scR[8], shR[8];
    {
        int b = TID & 3;
        #pragma unroll
        for (int j = 0; j < 8; j++) { scR[j] = scs[b * 8 + j]; shR[j] = shs[b * 8 + j]; }
    }
    short8 bw[25];
    #pragma unroll
    for (int sh = 0; sh < 25; sh++)
        bw[sh] = *reinterpret_cast<const short8*>(qw2c + ((size_t)sh * 64 + oc0 + lm) * 32 + bq * 8);
    int xy[5];
    #pragma unroll
    for (int kx = 0; kx < 5; kx++) {
        int xx = ox + kx;
        xy[kx] = lr * 784 + xx * 64 + (((bq + (xx >> 1)) & 3) * 16);
    }
    float sacc = 0.f, s2acc = 0.f;
    {
        const uint4* src = reinterpret_cast<const uint4*>(y1p + (size_t)n0 * 4608);
        #pragma unroll
        for (int k = 0; k < 3; k++) {
            if (k < 2 || TID < 64) {
                int i = TID + k * 256;
                int pix = i >> 2, b = i & 3;
                int y = pix / 12, xx = pix - y * 12;
                union { uint4 v; u16 u[8]; } in, out;
                in.v = src[i];
                #pragma unroll
                for (int j = 0; j < 8; j++)
                    out.u[j] = f2b(fmaxf(fmaf(b2f(in.u[j]), scR[j], shR[j]), 0.f));
                *reinterpret_cast<uint4*>(hsraw + y * 784 + xx * 64 + (((b + (xx >> 1)) & 3) * 16)) = out.v;
            }
        }
    }
    #pragma unroll 1
    for (int s = 0; s < 8; s++) {
        __syncthreads();
        if (s < 7) {
            const uint4* src = reinterpret_cast<const uint4*>(y1p + (size_t)(n0 + s + 1) * 4608);
            char* dst = hsraw + ((s + 1) & 1) * 9408;
            #pragma unroll
            for (int k = 0; k < 3; k++) {
                if (k < 2 || TID < 64) {
                    int i = TID + k * 256;
                    int pix = i >> 2, b = i & 3;
                    int y = pix / 12, xx = pix - y * 12;
                    union { uint4 v; u16 u[8]; } in, out;
                    in.v = src[i];
                    #pragma unroll
                    for (int j = 0; j < 8; j++)
                        out.u[j] = f2b(fmaxf(fmaf(b2f(in.u[j]), scR[j], shR[j]), 0.f));
                    *reinterpret_cast<uint4*>(dst + y * 784 + xx * 64 + (((b + (xx >> 1)) & 3) * 16)) = out.v;
                }
            }
        }
        const char* hb = hsraw + (s & 1) * 9408;
        f32x4 acc[4] = {{0.f,0.f,0.f,0.f},{0.f,0.f,0.f,0.f},{0.f,0.f,0.f,0.f},{0.f,0.f,0.f,0.f}};
        #pragma unroll
        for (int R = 0; R <= 10; R++) {
            short8 a[5];
            #pragma unroll
            for (int kx = 0; kx < 5; kx++)
                a[kx] = *reinterpret_cast<const short8*>(hb + xy[kx] + R * 784);
            #pragma unroll
            for (int mt = 0; mt < 4; mt++) {
                int ky = R - 2 * mt;
                if (ky < 0 || ky > 4) continue;
                #pragma unroll
                for (int kx = 0; kx < 5; kx++)
                    acc[mt] = __builtin_amdgcn_mfma_f32_16x16x32_bf16(a[kx], bw[ky * 5 + kx], acc[mt], 0, 0, 0);
            }
        }
        int n = n0 + s;
        u16* hp = h2pre + (size_t)n * 1024 + (oc0 + lm) * 16;
        #pragma unroll
        for (int mt = 0; mt < 4; mt++) {
            float v0 = acc[mt][0], v1 = acc[mt][1], v2 = acc[mt][2], v3 = acc[mt][3];
            sacc += v0 + v1 + v2 + v3;
            s2acc += v0 * v0 + v1 * v1 + v2 * v2 + v3 * v3;
            float w0 = fmaxf(v0, v1), w1 = fmaxf(v2, v3);
            float p0 = fmaxf(w0, __shfl_xor(w0, 32));
            float p1 = fmaxf(w1, __shfl_xor(w1, 32));
            if (bq < 2) {
                unsigned int u = (unsigned int)f2b(p0) | ((unsigned int)f2b(p1) << 16);
                *reinterpret_cast<unsigned int*>(hp + mt * 4 + bq * 2) = u;
            }
        }
    }
    sacc  += __shfl_xor(sacc, 16);  sacc  += __shfl_xor(sacc, 32);
    s2acc += __shfl_xor(s2acc, 16); s2acc += __shfl_xor(s2acc, 32);
    if (l < 16) { atomicAdd(&sum[oc0 + l], sacc); atomicAdd(&ssq[oc0 + l], s2acc); }
}

// ---------------- fc1: 64x64-tile MFMA GEMM; BN2+relu fused into A-staging ----------------
__global__ __launch_bounds__(256) void fc1_k(const u16* __restrict__ h2pre,
                                             const u16* __restrict__ qwf1c,
                                             const float* sum2, const float* ssq2,
                                             const float* g2, const float* be2,
                                             float* __restrict__ y3T,
                                             float* sum3, float* ssq3) {
    __shared__ float4 Asm[576], Bsm[576];
    __shared__ float sc2s[64], sh2s[64];
    u16* AsU = (u16*)Asm; u16* BsU = (u16*)Bsm;
    int m0 = blockIdx.x * 64, j0 = blockIdx.y * 64;
    int l = TID & 63, wv = TID >> 6;
    int lm = l & 15, q = l >> 4;
    int r0 = TID >> 3, c0 = TID & 7;
    if (TID < 64) {
        float m = sum2[TID] * (1.f / 262144.f);
        float v = ssq2[TID] * (1.f / 262144.f) - m * m;
        float s = g2[TID] / sqrtf(v + 1e-5f);
        sc2s[TID] = s; sh2s[TID] = be2[TID] - m * s;
    }
    __syncthreads();
    f32x4 acc[4] = {{0.f,0.f,0.f,0.f},{0.f,0.f,0.f,0.f},{0.f,0.f,0.f,0.f},{0.f,0.f,0.f,0.f}};
    #pragma unroll 1
    for (int kc = 0; kc < 16; kc++) {
        int kk = kc * 64;
        if (kc) __syncthreads();
        int oc = (kk + c0 * 8) >> 4;                 // one oc per 8-elem A load
        float sc = sc2s[oc], sh = sh2s[oc];
        #pragma unroll
        for (int i = 0; i < 2; i++) {
            int r = i * 32 + r0;
            union { float4 v; u16 h[8]; } in, o;
            in.v = *reinterpret_cast<const float4*>(h2pre + (size_t)(m0 + r) * 1024 + kk + c0 * 8);
            #pragma unroll
            for (int e = 0; e < 8; e++)
                o.h[e] = f2b(fmaxf(fmaf(b2f(in.h[e]), sc, sh), 0.f));
            *reinterpret_cast<float4*>(AsU + r * 72 + c0 * 8) = o.v;
            *reinterpret_cast<float4*>(BsU + r * 72 + c0 * 8) =
                *reinterpret_cast<const float4*>(qwf1c + (size_t)(j0 + r) * 1024 + kk + c0 * 8);
        }
        __syncthreads();
        #pragma unroll
        for (int half = 0; half < 2; half++) {
            short8 b = *reinterpret_cast<const short8*>(BsU + (wv * 16 + lm) * 72 + half * 32 + q * 8);
            #pragma unroll
            for (int mt = 0; mt < 4; mt++) {
                short8 a = *reinterpret_cast<const short8*>(AsU + (mt * 16 + lm) * 72 + half * 32 + q * 8);
                acc[mt] = __builtin_amdgcn_mfma_f32_16x16x32_bf16(a, b, acc[mt], 0, 0, 0);
            }
        }
    }
    float s = 0.f, s2 = 0.f;
    #pragma unroll
    for (int mt = 0; mt < 4; mt++) {
        *reinterpret_cast<f32x4*>(y3T + (size_t)(j0 + wv * 16 + lm) * 4096 + m0 + mt * 16 + q * 4) = acc[mt];
        #pragma unroll
        for (int i = 0; i < 4; i++) { float v = acc[mt][i]; s += v; s2 = fmaf(v, v, s2); }
    }
    s  += __shfl_xor(s, 16);  s  += __shfl_xor(s, 32);
    s2 += __shfl_xor(s2, 16); s2 += __shfl_xor(s2, 32);
    if (l < 16) {
        atomicAdd(&sum3[j0 + wv * 16 + l], s);
        atomicAdd(&ssq3[j0 + wv * 16 + l], s2);
    }
}

// ---------------- fc2: BN3 inline + relu + GEMV; grid 256 = 16 n x 16 kslices ----------------
__global__ __launch_bounds__(256) void fc2_k(const float* __restrict__ y3T,
                                             const float* sum3, const float* ssq3,
                                             const float* g3, const float* be3,
                                             const float* __restrict__ qwf2,
                                             const float* bf2, float* __restrict__ out) {
    __shared__ float wlds[5120];
    __shared__ float part[15][160];
    __shared__ float sc3s[512], sh3s[512];
    for (int i = TID; i < 5120; i += 256) wlds[i] = qwf2[i];
    for (int k = TID; k < 512; k += 256) {
        float m = sum3[k] * (1.f / 4096.f);
        float v = ssq3[k] * (1.f / 4096.f) - m * m;
        float s = g3[k] / sqrtf(v + 1e-5f);
        sc3s[k] = s; sh3s[k] = be3[k] - m * s;
    }
    __syncthreads();
    int nl = TID & 15, ks = TID >> 4;
    int n = blockIdx.x * 16 + nl;            // grid.x = 256
    float acc[10] = {};
    for (int k = ks * 32; k < ks * 32 + 32; k++) {
        float v = fmaxf(y3T[(size_t)k * 4096 + n] * sc3s[k] + sh3s[k], 0.f);
        #pragma unroll
        for (int o = 0; o < 10; o++) acc[o] = fmaf(v, wlds[o * 512 + k], acc[o]);
    }
    if (ks > 0) {
        #pragma unroll
        for (int o = 0; o < 10; o++) part[ks - 1][o * 16 + nl] = acc[o];
    }
    __syncthreads();
    if (ks == 0) {
        #pragma unroll
        for (int o = 0; o < 10; o++) {
            float r = acc[o] + bf2[o];
            #pragma unroll
            for (int j = 0; j < 15; j++) r += part[j][o * 16 + nl];
            out[n * 10 + o] = r;
        }
    }
}

extern "C" void kernel_launch(void* const* d_in, const int* in_sizes, int n_in,
                              void* d_out, int out_size, void* d_ws, size_t ws_size,
                              hipStream_t stream) {
    char* wsb = (char*)d_ws;
    const float* x   = (const float*)d_in[0];
    const float* w1  = (const float*)d_in[1];
    // b1/b2/bf1 cancel under training-mode BN
    const float* g1  = (const float*)d_in[3];
    const float* be1 = (const float*)d_in[4];
    const float* w2  = (const float*)d_in[5];
    const float* g2  = (const float*)d_in[7];
    const float* be2 = (const float*)d_in[8];
    const float* wf1 = (const float*)d_in[9];
    const float* g3  = (const float*)d_in[11];
    const float* be3 = (const float*)d_in[12];
    const float* wf2 = (const float*)d_in[13];
    const float* bf2 = (const float*)d_in[14];
    float* out = (float*)d_out;

    unsigned int* tmax = (unsigned int*)(wsb + OFF_TMAX);
    float* qw1   = (float*)(wsb + OFF_QW1);
    float* qwf2  = (float*)(wsb + OFF_QWF2);
    u16*   qw2c  = (u16*)(wsb + OFF_QW2C);
    u16*   qwf1c = (u16*)(wsb + OFF_QWF1C);
    u16*   y1p   = (u16*)(wsb + OFF_Y1P);
    u16*   h2pre = (u16*)(wsb + OFF_H2P);
    float* y3    = (float*)(wsb + OFF_Y3);

    float* sum1c = (float*)(wsb + OFF_SUM1C); float* ssq1c = (float*)(wsb + OFF_SSQ1C);
    float* sum2  = (float*)(wsb + OFF_SUM2);  float* ssq2  = (float*)(wsb + OFF_SSQ2);
    float* sum3  = (float*)(wsb + OFF_SUM3);  float* ssq3  = (float*)(wsb + OFF_SSQ3);

    hipMemsetAsync(wsb + STATS_BEG, 0, STATS_END - STATS_BEG, stream);

    absmax_k<<<266, 256, 0, stream>>>(w1, w2, wf1, wf2, tmax);
    quant_all_k<<<2272, 256, 0, stream>>>(w1, w2, wf1, wf2, qw1, qw2c, qwf1c, qwf2, tmax);

    conv1_fused_k<<<6144, 256, 0, stream>>>(x, qw1, y1p, sum1c, ssq1c);
    conv2_k<<<512, 256, 0, stream>>>(y1p, qw2c, h2pre, sum1c, ssq1c, g1, be1, sum2, ssq2);
    fc1_k<<<dim3(64, 8), 256, 0, stream>>>(h2pre, qwf1c, sum2, ssq2, g2, be2, y3, sum3, ssq3);
    fc2_k<<<256, 256, 0, stream>>>(y3, sum3, ssq3, g3, be3, qwf2, bf2, out);
}

// Round 18
// 211.319 us; speedup vs baseline: 1.6213x; 1.0703x over previous
//
#include <hip/hip_runtime.h>

#define TID ((int)threadIdx.x)
typedef unsigned short u16;
typedef short short8 __attribute__((ext_vector_type(8)));
typedef float f32x4 __attribute__((ext_vector_type(4)));

__device__ __forceinline__ u16 f2b(float f) {
    unsigned int x = __float_as_uint(f);
    return (u16)((x + 0x7fffu + ((x >> 16) & 1u)) >> 16);
}
__device__ __forceinline__ float b2f(u16 u) {
    return __uint_as_float(((unsigned int)u) << 16);
}

// ---------------- workspace layout (BYTE offsets) ----------------
static constexpr size_t OFF_QW1   = 0;         // 800 f32 [32][25]
static constexpr size_t OFF_QWF2  = 3200;      // 5120 f32 [10][512]
static constexpr size_t OFF_TMAX  = 23680;     // 4 uint
static constexpr size_t OFF_SUM1C = 23808;     // f32 [8 copies][32]
static constexpr size_t OFF_SSQ1C = 24832;     // f32 [8][32]
static constexpr size_t OFF_SUM2  = 25856, OFF_SSQ2 = 26112;   // f32 [64]
static constexpr size_t OFF_SUM3  = 26368, OFF_SSQ3 = 28416;   // f32 [512]
static constexpr size_t STATS_BEG = 23680, STATS_END = 30464;
static constexpr size_t OFF_QW2C  = 30720;     // bf16 [25 shift][64 oc][32 ic]
static constexpr size_t OFF_QWF1C = 133120;    // bf16 [512][1024]
static constexpr size_t OFF_Y1P   = 1181696;   // bf16 [4096][144][32]  PRE-BN pooled conv1
static constexpr size_t OFF_H2P   = 38930432;  // bf16 [4096][1024]     PRE-BN pooled conv2
static constexpr size_t OFF_Y3    = 47319040;  // f32 [512][4096]
// total ~55.7 MB

// ---------------- abs-max of the 4 weight tensors ----------------
__global__ __launch_bounds__(256) void absmax_k(const float* w1, const float* w2,
                                                const float* wf1, const float* wf2,
                                                unsigned int* tmaxbits) {
    int bid = blockIdx.x;
    int b, lb, nb; const float* src; long n;
    if (bid < 1)        { b = 0; src = w1;  n = 800;    lb = bid;       nb = 1;   }
    else if (bid < 9)   { b = 1; src = w2;  n = 51200;  lb = bid - 1;   nb = 8;   }
    else if (bid < 265) { b = 2; src = wf1; n = 524288; lb = bid - 9;   nb = 256; }
    else                { b = 3; src = wf2; n = 5120;   lb = bid - 265; nb = 1;   }
    float m = 0.f;
    for (long i = (long)lb * 256 + TID; i < n; i += (long)nb * 256)
        m = fmaxf(m, fabsf(src[i]));
    __shared__ float red[256];
    red[TID] = m; __syncthreads();
    for (int s = 128; s > 0; s >>= 1) {
        if (TID < s) red[TID] = fmaxf(red[TID], red[TID + s]);
        __syncthreads();
    }
    if (TID == 0) atomicMax(&tmaxbits[b], __float_as_uint(red[0]));
}

// ---------------- all 4 quantizers in one launch ----------------
__global__ __launch_bounds__(256) void quant_all_k(const float* w1, const float* w2,
                                                   const float* wf1, const float* wf2,
                                                   float* qw1, u16* qw2c, u16* qwf1c,
                                                   float* qwf2, const unsigned int* tmax) {
    int bid = blockIdx.x;
    if (bid < 4) {
        int i = bid * 256 + TID; if (i >= 800) return;
        float t = 0.05f * __uint_as_float(tmax[0]);
        float v = w1[i];
        qw1[i] = (v > t) ? 1.f : ((v < -t) ? -1.f : 0.f);
    } else if (bid < 204) {
        int i = (bid - 4) * 256 + TID;       // < 51200
        float t = 0.05f * __uint_as_float(tmax[1]);
        int ic = i & 31, oc = (i >> 5) & 63, sh = i >> 11;
        float v = w2[(oc * 32 + ic) * 25 + sh];
        qw2c[i] = f2b((v > t) ? 1.f : ((v < -t) ? -1.f : 0.f));
    } else if (bid < 2252) {
        int i = (bid - 204) * 256 + TID;     // < 524288
        float t = 0.05f * __uint_as_float(tmax[2]);
        float v = wf1[i];
        qwf1c[i] = f2b((v > t) ? 1.f : ((v < -t) ? -1.f : 0.f));
    } else {
        int i = (bid - 2252) * 256 + TID;    // < 5120
        float t = 0.05f * __uint_as_float(tmax[3]);
        float v = wf2[i];
        qwf2[i] = (v > t) ? 1.f : ((v < -t) ? -1.f : 0.f);
    }
}

// ---------------- conv1 via MFMA, samples-as-M ----------------
// Block = 16 samples x (6 pooled rows [ph]) x (6 pooled cols [pch]); grid 1024.
// MFMA: A[m=sample][k=q*8+kx] from contiguous LDS row reads; B[k][n=ch] zero-padded
// taps (validated in r14). 2 col-shifted replicas (b32 align); sample stride 1096 u16
// => words ≡ 4 mod 32 => cycle-group lanes hit 8 distinct banks (conflict-free).
// D rows=samples, cols=channels => 2x2 pool fully in-register; stats per-lane+shfl.
// xs fully pre-zeroed (r14 NaN lesson: replica tails must be finite).
__global__ __launch_bounds__(256) void conv1_fused_k(const float* __restrict__ x,
                                                     const float* __restrict__ qw1,
                                                     u16* __restrict__ y1p,
                                                     float* sum1c, float* ssq1c) {
    __shared__ __align__(16) u16 xs[16 * 1096];  // [16 smp][rep0 548 | rep1 548]
    int gid = blockIdx.x;                        // 1024 = 256 sg x 2 ph x 2 pch
    int sg = gid >> 2, ph = (gid >> 1) & 1, pch = gid & 1;
    int l = TID & 63, w = TID >> 6;
    int lm = l & 15, q = l >> 4;

    // ---- zero-fill (2192 uint4) ----
    #pragma unroll
    for (int i = 0; i < 9; i++) {
        int idx = TID + i * 256;
        if (idx < 2192) reinterpret_cast<uint4*>(xs)[idx] = make_uint4(0, 0, 0, 0);
    }

    // ---- B fragments (global reads, no LDS dep) ----
    short8 B1[2], B2[2];
    #pragma unroll
    for (int c = 0; c < 2; c++) {
        union { short8 s; u16 h[8]; } b1, b2;
        int ch = c * 16 + lm;
        #pragma unroll
        for (int j = 0; j < 8; j++) {
            float v1 = 0.f, v2 = 0.f;
            if (j < 5) {
                v1 = qw1[ch * 25 + q * 5 + j];
                v2 = qw1[ch * 25 + 20 + j];
            }
            b1.h[j] = f2b(v1);
            b2.h[j] = (q == 0) ? f2b(v2) : (u16)0;
        }
        B1[c] = b1.s; B2[c] = b2.s;
    }
    __syncthreads();

    // ---- stage x rows 12ph..12ph+15 as bf16, 2 shifted replicas ----
    #pragma unroll
    for (int k = 0; k < 7; k++) {
        int i = TID + k * 256;                   // < 1792 exactly
        int smp = i / 112, rem = i % 112;
        int row = rem / 7, c4 = (rem % 7) * 4;
        float4 v = *reinterpret_cast<const float4*>(
            x + (size_t)(sg * 16 + smp) * 784 + (12 * ph + row) * 28 + c4);
        u16 h[4] = {f2b(v.x), f2b(v.y), f2b(v.z), f2b(v.w)};
        union { uint2 u; u16 hh[4]; } pk;
        pk.hh[0] = h[0]; pk.hh[1] = h[1]; pk.hh[2] = h[2]; pk.hh[3] = h[3];
        *reinterpret_cast<uint2*>(xs + smp * 1096 + row * 32 + c4) = pk.u;
        u16* b1p = xs + smp * 1096 + 548 + row * 32;
        #pragma unroll
        for (int e = 0; e < 4; e++) {
            int c = c4 + e;
            if (c >= 1) b1p[c - 1] = h[e];
        }
    }
    __syncthreads();

    // ---- compute: wave w handles 9 pooled positions ----
    float s0 = 0.f, s1 = 0.f, q0 = 0.f, q1 = 0.f;
    int laneoff = lm * 1096;
    #pragma unroll 1
    for (int e = 0; e < 9; e++) {
        int pp = w * 9 + e;                      // 0..35
        int prl = pp / 6, pcl = pp - prl * 6;
        f32x4 pm0 = {-3.0e38f, -3.0e38f, -3.0e38f, -3.0e38f};
        f32x4 pm1 = pm0;
        #pragma unroll
        for (int dyx = 0; dyx < 4; dyx++) {
            int dy = dyx >> 1, dx = dyx & 1;
            int oyl = 2 * prl + dy;              // local conv row 0..11
            int ox = 2 * (pch * 6 + pcl) + dx;   // global conv col 0..23
            int r = ox & 1, cb = ox - r;
            const u16* p1 = xs + laneoff + r * 548 + (oyl + q) * 32 + cb;
            const u16* p2 = xs + laneoff + r * 548 + (oyl + 4) * 32 + cb;
            union { short8 s; unsigned int u[4]; } a1, a2;
            #pragma unroll
            for (int t = 0; t < 4; t++) {
                a1.u[t] = *reinterpret_cast<const unsigned int*>(p1 + 2 * t);
                a2.u[t] = *reinterpret_cast<const unsigned int*>(p2 + 2 * t);
            }
            f32x4 d0 = {0.f, 0.f, 0.f, 0.f};
            d0 = __builtin_amdgcn_mfma_f32_16x16x32_bf16(a1.s, B1[0], d0, 0, 0, 0);
            d0 = __builtin_amdgcn_mfma_f32_16x16x32_bf16(a2.s, B2[0], d0, 0, 0, 0);
            f32x4 d1 = {0.f, 0.f, 0.f, 0.f};
            d1 = __builtin_amdgcn_mfma_f32_16x16x32_bf16(a1.s, B1[1], d1, 0, 0, 0);
            d1 = __builtin_amdgcn_mfma_f32_16x16x32_bf16(a2.s, B2[1], d1, 0, 0, 0);
            #pragma unroll
            for (int i = 0; i < 4; i++) {
                float v = d0[i]; s0 += v; q0 = fmaf(v, v, q0);
                float u = d1[i]; s1 += u; q1 = fmaf(u, u, q1);
            }
            pm0 = __builtin_elementwise_max(pm0, d0);
            pm1 = __builtin_elementwise_max(pm1, d1);
        }
        int ppg = (ph * 6 + prl) * 12 + (pch * 6 + pcl);
        #pragma unroll
        for (int i = 0; i < 4; i++) {
            size_t nb = (size_t)(sg * 16 + 4 * q + i) * 4608 + ppg * 32;
            y1p[nb + lm]      = f2b(pm0[i]);
            y1p[nb + 16 + lm] = f2b(pm1[i]);
        }
    }
    // ---- stats: lanes l, l^16, l^32, l^48 share channel (sum over 16 samples) ----
    s0 += __shfl_xor(s0, 16); s0 += __shfl_xor(s0, 32);
    s1 += __shfl_xor(s1, 16); s1 += __shfl_xor(s1, 32);
    q0 += __shfl_xor(q0, 16); q0 += __shfl_xor(q0, 32);
    q1 += __shfl_xor(q1, 16); q1 += __shfl_xor(q1, 32);
    if (l < 16) {
        int slot = (blockIdx.x & 7) * 32;
        atomicAdd(&sum1c[slot + l], s0);
        atomicAdd(&sum1c[slot + 16 + l], s1);
        atomicAdd(&ssq1c[slot + l], q0);
        atomicAdd(&ssq1c[slot + 16 + l], q1);
    }
}

// ---------------- conv2: MFMA implicit conv; BN1+relu in staging; pre-BN pooled epilogue ----------------
__global__ __launch_bounds__(256) void conv2_k(const u16* __restrict__ y1p,
                                               const u16* __restrict__ qw2c,
                                               u16* __restrict__ h2pre,
                                               const float* sum1c, const float* ssq1c,
                                               const float* g1, const float* be1,
                                               float* sum, float* ssq) {
    __shared__ float4 hsm4[1176];            // 2 x 9408 B
    __shared__ float scs[32], shs[32];
    char* hsraw = (char*)hsm4;
    int n0 = blockIdx.x * 8;                 // grid.x = 512
    int l = TID & 63, wv = TID >> 6;
    int oc0 = wv * 16;
    int lm = l & 15, lr = (l >> 3) & 1, ox = l & 7, bq = l >> 4;
    if (TID < 32) {
        float s = 0.f, q = 0.f;
        #pragma unroll
        for (int r = 0; r < 8; r++) { s += sum1c[r * 32 + TID]; q += ssq1c[r * 32 + TID]; }
        float m = s * (1.f / 2359296.f);
        float v = q * (1.f / 2359296.f) - m * m;
        float sc = g1[TID] / sqrtf(v + 1e-5f);
        scs[TID] = sc; shs[TID] = be1[TID] - m * sc;
    }
    __syncthreads();
    float scR[8], shR[8];
    {
        int b = TID & 3;
        #pragma unroll
        for (int j = 0; j < 8; j++) { scR[j] = scs[b * 8 + j]; shR[j] = shs[b * 8 + j]; }
    }
    short8 bw[25];
    #pragma unroll
    for (int sh = 0; sh < 25; sh++)
        bw[sh] = *reinterpret_cast<const short8*>(qw2c + ((size_t)sh * 64 + oc0 + lm) * 32 + bq * 8);
    int xy[5];
    #pragma unroll
    for (int kx = 0; kx < 5; kx++) {
        int xx = ox + kx;
        xy[kx] = lr * 784 + xx * 64 + (((bq + (xx >> 1)) & 3) * 16);
    }
    float sacc = 0.f, s2acc = 0.f;
    {
        const uint4* src = reinterpret_cast<const uint4*>(y1p + (size_t)n0 * 4608);
        #pragma unroll
        for (int k = 0; k < 3; k++) {
            if (k < 2 || TID < 64) {
                int i = TID + k * 256;
                int pix = i >> 2, b = i & 3;
                int y = pix / 12, xx = pix - y * 12;
                union { uint4 v; u16 u[8]; } in, out;
                in.v = src[i];
                #pragma unroll
                for (int j = 0; j < 8; j++)
                    out.u[j] = f2b(fmaxf(fmaf(b2f(in.u[j]), scR[j], shR[j]), 0.f));
                *reinterpret_cast<uint4*>(hsraw + y * 784 + xx * 64 + (((b + (xx >> 1)) & 3) * 16)) = out.v;
            }
        }
    }
    #pragma unroll 1
    for (int s = 0; s < 8; s++) {
        __syncthreads();
        if (s < 7) {
            const uint4* src = reinterpret_cast<const uint4*>(y1p + (size_t)(n0 + s + 1) * 4608);
            char* dst = hsraw + ((s + 1) & 1) * 9408;
            #pragma unroll
            for (int k = 0; k < 3; k++) {
                if (k < 2 || TID < 64) {
                    int i = TID + k * 256;
                    int pix = i >> 2, b = i & 3;
                    int y = pix / 12, xx = pix - y * 12;
                    union { uint4 v; u16 u[8]; } in, out;
                    in.v = src[i];
                    #pragma unroll
                    for (int j = 0; j < 8; j++)
                        out.u[j] = f2b(fmaxf(fmaf(b2f(in.u[j]), scR[j], shR[j]), 0.f));
                    *reinterpret_cast<uint4*>(dst + y * 784 + xx * 64 + (((b + (xx >> 1)) & 3) * 16)) = out.v;
                }
            }
        }
        const char* hb = hsraw + (s & 1) * 9408;
        f32x4 acc[4] = {{0.f,0.f,0.f,0.f},{0.f,0.f,0.f,0.f},{0.f,0.f,0.f,0.f},{0.f,0.f,0.f,0.f}};
        #pragma unroll
        for (int R = 0; R <= 10; R++) {
            short8 a[5];
            #pragma unroll
            for (int kx = 0; kx < 5; kx++)
                a[kx] = *reinterpret_cast<const short8*>(hb + xy[kx] + R * 784);
            #pragma unroll
            for (int mt = 0; mt < 4; mt++) {
                int ky = R - 2 * mt;
                if (ky < 0 || ky > 4) continue;
                #pragma unroll
                for (int kx = 0; kx < 5; kx++)
                    acc[mt] = __builtin_amdgcn_mfma_f32_16x16x32_bf16(a[kx], bw[ky * 5 + kx], acc[mt], 0, 0, 0);
            }
        }
        int n = n0 + s;
        u16* hp = h2pre + (size_t)n * 1024 + (oc0 + lm) * 16;
        #pragma unroll
        for (int mt = 0; mt < 4; mt++) {
            float v0 = acc[mt][0], v1 = acc[mt][1], v2 = acc[mt][2], v3 = acc[mt][3];
            sacc += v0 + v1 + v2 + v3;
            s2acc += v0 * v0 + v1 * v1 + v2 * v2 + v3 * v3;
            float w0 = fmaxf(v0, v1), w1 = fmaxf(v2, v3);
            float p0 = fmaxf(w0, __shfl_xor(w0, 32));
            float p1 = fmaxf(w1, __shfl_xor(w1, 32));
            if (bq < 2) {
                unsigned int u = (unsigned int)f2b(p0) | ((unsigned int)f2b(p1) << 16);
                *reinterpret_cast<unsigned int*>(hp + mt * 4 + bq * 2) = u;
            }
        }
    }
    sacc  += __shfl_xor(sacc, 16);  sacc  += __shfl_xor(sacc, 32);
    s2acc += __shfl_xor(s2acc, 16); s2acc += __shfl_xor(s2acc, 32);
    if (l < 16) { atomicAdd(&sum[oc0 + l], sacc); atomicAdd(&ssq[oc0 + l], s2acc); }
}

// ---------------- fc1: 64x64-tile MFMA GEMM; BN2+relu fused into A-staging ----------------
__global__ __launch_bounds__(256) void fc1_k(const u16* __restrict__ h2pre,
                                             const u16* __restrict__ qwf1c,
                                             const float* sum2, const float* ssq2,
                                             const float* g2, const float* be2,
                                             float* __restrict__ y3T,
                                             float* sum3, float* ssq3) {
    __shared__ float4 Asm[576], Bsm[576];
    __shared__ float sc2s[64], sh2s[64];
    u16* AsU = (u16*)Asm; u16* BsU = (u16*)Bsm;
    int m0 = blockIdx.x * 64, j0 = blockIdx.y * 64;
    int l = TID & 63, wv = TID >> 6;
    int lm = l & 15, q = l >> 4;
    int r0 = TID >> 3, c0 = TID & 7;
    if (TID < 64) {
        float m = sum2[TID] * (1.f / 262144.f);
        float v = ssq2[TID] * (1.f / 262144.f) - m * m;
        float s = g2[TID] / sqrtf(v + 1e-5f);
        sc2s[TID] = s; sh2s[TID] = be2[TID] - m * s;
    }
    __syncthreads();
    f32x4 acc[4] = {{0.f,0.f,0.f,0.f},{0.f,0.f,0.f,0.f},{0.f,0.f,0.f,0.f},{0.f,0.f,0.f,0.f}};
    #pragma unroll 1
    for (int kc = 0; kc < 16; kc++) {
        int kk = kc * 64;
        if (kc) __syncthreads();
        int oc = (kk + c0 * 8) >> 4;
        float sc = sc2s[oc], sh = sh2s[oc];
        #pragma unroll
        for (int i = 0; i < 2; i++) {
            int r = i * 32 + r0;
            union { float4 v; u16 h[8]; } in, o;
            in.v = *reinterpret_cast<const float4*>(h2pre + (size_t)(m0 + r) * 1024 + kk + c0 * 8);
            #pragma unroll
            for (int e = 0; e < 8; e++)
                o.h[e] = f2b(fmaxf(fmaf(b2f(in.h[e]), sc, sh), 0.f));
            *reinterpret_cast<float4*>(AsU + r * 72 + c0 * 8) = o.v;
            *reinterpret_cast<float4*>(BsU + r * 72 + c0 * 8) =
                *reinterpret_cast<const float4*>(qwf1c + (size_t)(j0 + r) * 1024 + kk + c0 * 8);
        }
        __syncthreads();
        #pragma unroll
        for (int half = 0; half < 2; half++) {
            short8 b = *reinterpret_cast<const short8*>(BsU + (wv * 16 + lm) * 72 + half * 32 + q * 8);
            #pragma unroll
            for (int mt = 0; mt < 4; mt++) {
                short8 a = *reinterpret_cast<const short8*>(AsU + (mt * 16 + lm) * 72 + half * 32 + q * 8);
                acc[mt] = __builtin_amdgcn_mfma_f32_16x16x32_bf16(a, b, acc[mt], 0, 0, 0);
            }
        }
    }
    float s = 0.f, s2 = 0.f;
    #pragma unroll
    for (int mt = 0; mt < 4; mt++) {
        *reinterpret_cast<f32x4*>(y3T + (size_t)(j0 + wv * 16 + lm) * 4096 + m0 + mt * 16 + q * 4) = acc[mt];
        #pragma unroll
        for (int i = 0; i < 4; i++) { float v = acc[mt][i]; s += v; s2 = fmaf(v, v, s2); }
    }
    s  += __shfl_xor(s, 16);  s  += __shfl_xor(s, 32);
    s2 += __shfl_xor(s2, 16); s2 += __shfl_xor(s2, 32);
    if (l < 16) {
        atomicAdd(&sum3[j0 + wv * 16 + l], s);
        atomicAdd(&ssq3[j0 + wv * 16 + l], s2);
    }
}

// ---------------- fc2: BN3 inline + relu + GEMV; grid 256 = 16 n x 16 kslices ----------------
__global__ __launch_bounds__(256) void fc2_k(const float* __restrict__ y3T,
                                             const float* sum3, const float* ssq3,
                                             const float* g3, const float* be3,
                                             const float* __restrict__ qwf2,
                                             const float* bf2, float* __restrict__ out) {
    __shared__ float wlds[5120];
    __shared__ float part[15][160];
    __shared__ float sc3s[512], sh3s[512];
    for (int i = TID; i < 5120; i += 256) wlds[i] = qwf2[i];
    for (int k = TID; k < 512; k += 256) {
        float m = sum3[k] * (1.f / 4096.f);
        float v = ssq3[k] * (1.f / 4096.f) - m * m;
        float s = g3[k] / sqrtf(v + 1e-5f);
        sc3s[k] = s; sh3s[k] = be3[k] - m * s;
    }
    __syncthreads();
    int nl = TID & 15, ks = TID >> 4;
    int n = blockIdx.x * 16 + nl;            // grid.x = 256
    float acc[10] = {};
    for (int k = ks * 32; k < ks * 32 + 32; k++) {
        float v = fmaxf(y3T[(size_t)k * 4096 + n] * sc3s[k] + sh3s[k], 0.f);
        #pragma unroll
        for (int o = 0; o < 10; o++) acc[o] = fmaf(v, wlds[o * 512 + k], acc[o]);
    }
    if (ks > 0) {
        #pragma unroll
        for (int o = 0; o < 10; o++) part[ks - 1][o * 16 + nl] = acc[o];
    }
    __syncthreads();
    if (ks == 0) {
        #pragma unroll
        for (int o = 0; o < 10; o++) {
            float r = acc[o] + bf2[o];
            #pragma unroll
            for (int j = 0; j < 15; j++) r += part[j][o * 16 + nl];
            out[n * 10 + o] = r;
        }
    }
}

extern "C" void kernel_launch(void* const* d_in, const int* in_sizes, int n_in,
                              void* d_out, int out_size, void* d_ws, size_t ws_size,
                              hipStream_t stream) {
    char* wsb = (char*)d_ws;
    const float* x   = (const float*)d_in[0];
    const float* w1  = (const float*)d_in[1];
    // b1/b2/bf1 cancel under training-mode BN
    const float* g1  = (const float*)d_in[3];
    const float* be1 = (const float*)d_in[4];
    const float* w2  = (const float*)d_in[5];
    const float* g2  = (const float*)d_in[7];
    const float* be2 = (const float*)d_in[8];
    const float* wf1 = (const float*)d_in[9];
    const float* g3  = (const float*)d_in[11];
    const float* be3 = (const float*)d_in[12];
    const float* wf2 = (const float*)d_in[13];
    const float* bf2 = (const float*)d_in[14];
    float* out = (float*)d_out;

    unsigned int* tmax = (unsigned int*)(wsb + OFF_TMAX);
    float* qw1   = (float*)(wsb + OFF_QW1);
    float* qwf2  = (float*)(wsb + OFF_QWF2);
    u16*   qw2c  = (u16*)(wsb + OFF_QW2C);
    u16*   qwf1c = (u16*)(wsb + OFF_QWF1C);
    u16*   y1p   = (u16*)(wsb + OFF_Y1P);
    u16*   h2pre = (u16*)(wsb + OFF_H2P);
    float* y3    = (float*)(wsb + OFF_Y3);

    float* sum1c = (float*)(wsb + OFF_SUM1C); float* ssq1c = (float*)(wsb + OFF_SSQ1C);
    float* sum2  = (float*)(wsb + OFF_SUM2);  float* ssq2  = (float*)(wsb + OFF_SSQ2);
    float* sum3  = (float*)(wsb + OFF_SUM3);  float* ssq3  = (float*)(wsb + OFF_SSQ3);

    hipMemsetAsync(wsb + STATS_BEG, 0, STATS_END - STATS_BEG, stream);

    absmax_k<<<266, 256, 0, stream>>>(w1, w2, wf1, wf2, tmax);
    quant_all_k<<<2272, 256, 0, stream>>>(w1, w2, wf1, wf2, qw1, qw2c, qwf1c, qwf2, tmax);

    conv1_fused_k<<<1024, 256, 0, stream>>>(x, qw1, y1p, sum1c, ssq1c);
    conv2_k<<<512, 256, 0, stream>>>(y1p, qw2c, h2pre, sum1c, ssq1c, g1, be1, sum2, ssq2);
    fc1_k<<<dim3(64, 8), 256, 0, stream>>>(h2pre, qwf1c, sum2, ssq2, g2, be2, y3, sum3, ssq3);
    fc2_k<<<256, 256, 0, stream>>>(y3, sum3, ssq3, g3, be3, qwf2, bf2, out);
}